// Round 1
// baseline (461.659 us; speedup 1.0000x reference)
//
#include <hip/hip_runtime.h>

// 192^3 FDTD, FUSED: one kernel does step1 (E->H) into LDS (tile + 1-halo),
// then step2 (H->E) from LDS. Central differences defined only on the strict
// interior of all three dims; boundary points get zero curl contribution.
//
// Traffic floor: 9 inputs read once + 6 outputs written once = 424.7 MB
// (vs ~510-595 MB for the two-pass version whose E re-reads / H2 round-trip
// spill out of the 256 MB L3).

#define NXD 192
#define NYD 192
#define NZD 192

static constexpr int   N3    = NXD * NYD * NZD;   // 7,077,888
static constexpr float DTc   = 1e-12f;
static constexpr float INV2D = 500.0f;            // 1/(2*1e-3)

static constexpr int SX = NYD * NZD;  // x-axis stride
static constexpr int SY = NZD;        // y-axis stride

// Tile geometry: 4 x 8 x 32 interior points per block (1024), 256 threads.
static constexpr int TX = 4, TY = 8, TZ = 32;
static constexpr int HXT = TX + 2, HYT = TY + 2, HZT = TZ + 2;  // 6,10,34
static constexpr int HVOL = HXT * HYT * HZT;                    // 2040
static constexpr int TVOL = TX * TY * TZ;                       // 1024
static constexpr int NBX = NXD / TX, NBY = NYD / TY, NBZ = NZD / TZ; // 48,24,6
static constexpr int NBLK = NBX * NBY * NBZ;                    // 6912 (%8==0)

__global__ __launch_bounds__(256) void fdtd_fused(
    const float* __restrict__ Ex, const float* __restrict__ Ey, const float* __restrict__ Ez,
    const float* __restrict__ Hx, const float* __restrict__ Hy, const float* __restrict__ Hz,
    const float* __restrict__ eps, const float* __restrict__ mu, const float* __restrict__ sigma,
    float* __restrict__ Ex2, float* __restrict__ Ey2, float* __restrict__ Ez2,
    float* __restrict__ Hx2, float* __restrict__ Hy2, float* __restrict__ Hz2)
{
    __shared__ float sHx[HVOL];
    __shared__ float sHy[HVOL];
    __shared__ float sHz[HVOL];

    // XCD-bijective block swizzle: each XCD gets a contiguous chunk of the
    // z-y-x ordered grid so halo-overlapping neighbor tiles share an L2.
    int bid = blockIdx.x;
    int swz = (bid & 7) * (NBLK / 8) + (bid >> 3);

    int bz = swz % NBZ;
    int t  = swz / NBZ;
    int by = t % NBY;
    int bx = t / NBY;
    int ox = bx * TX, oy = by * TY, oz = bz * TZ;

    int tid = threadIdx.x;

    // ---------------- phase 1: H2 on tile + 1-halo -> LDS ----------------
    #pragma unroll
    for (int it = 0; it < (HVOL + 255) / 256; ++it) {
        int h = tid + it * 256;
        if (h < HVOL) {
            int hz = h % HZT;
            int tt = h / HZT;
            int hy = tt % HYT;
            int hx = tt / HYT;
            int gi = ox + hx - 1;
            int gj = oy + hy - 1;
            int gk = oz + hz - 1;

            float vx = 0.0f, vy = 0.0f, vz = 0.0f;
            if (gi >= 0 && gi < NXD && gj >= 0 && gj < NYD && gk >= 0 && gk < NZD) {
                int gidx = (gi * NYD + gj) * NZD + gk;
                float cx = 0.0f, cy = 0.0f, cz = 0.0f;
                if (gi > 0 && gi < NXD - 1 && gj > 0 && gj < NYD - 1 && gk > 0 && gk < NZD - 1) {
                    float dEz_dy = (Ez[gidx + SY] - Ez[gidx - SY]) * INV2D;
                    float dEy_dz = (Ey[gidx + 1 ] - Ey[gidx - 1 ]) * INV2D;
                    float dEx_dz = (Ex[gidx + 1 ] - Ex[gidx - 1 ]) * INV2D;
                    float dEz_dx = (Ez[gidx + SX] - Ez[gidx - SX]) * INV2D;
                    float dEy_dx = (Ey[gidx + SX] - Ey[gidx - SX]) * INV2D;
                    float dEx_dy = (Ex[gidx + SY] - Ex[gidx - SY]) * INV2D;
                    cx = dEz_dy - dEy_dz;
                    cy = dEx_dz - dEz_dx;
                    cz = dEy_dx - dEx_dy;
                }
                float f = DTc / mu[gidx];
                vx = Hx[gidx] - f * cx;
                vy = Hy[gidx] - f * cy;
                vz = Hz[gidx] - f * cz;
            }
            sHx[h] = vx;
            sHy[h] = vy;
            sHz[h] = vz;
        }
    }

    __syncthreads();

    // ---------------- phase 2: curl(H2) from LDS, write all outputs ------
    #pragma unroll
    for (int it = 0; it < TVOL / 256; ++it) {
        int q  = tid + it * 256;
        int iz = q % TZ;
        int tt = q / TZ;
        int iy = tt % TY;
        int ix = tt / TY;
        int gi = ox + ix, gj = oy + iy, gk = oz + iz;
        int gidx = (gi * NYD + gj) * NZD + gk;

        int l = ((ix + 1) * HYT + (iy + 1)) * HZT + (iz + 1);

        float hx2 = sHx[l];
        float hy2 = sHy[l];
        float hz2 = sHz[l];
        Hx2[gidx] = hx2;
        Hy2[gidx] = hy2;
        Hz2[gidx] = hz2;

        float cx = 0.0f, cy = 0.0f, cz = 0.0f;
        if (gi > 0 && gi < NXD - 1 && gj > 0 && gj < NYD - 1 && gk > 0 && gk < NZD - 1) {
            float dHz_dy = (sHz[l + HZT]       - sHz[l - HZT])       * INV2D;
            float dHy_dz = (sHy[l + 1]         - sHy[l - 1])         * INV2D;
            float dHx_dz = (sHx[l + 1]         - sHx[l - 1])         * INV2D;
            float dHz_dx = (sHz[l + HYT * HZT] - sHz[l - HYT * HZT]) * INV2D;
            float dHy_dx = (sHy[l + HYT * HZT] - sHy[l - HYT * HZT]) * INV2D;
            float dHx_dy = (sHx[l + HZT]       - sHx[l - HZT])       * INV2D;
            cx = dHz_dy - dHy_dz;
            cy = dHx_dz - dHz_dx;
            cz = dHy_dx - dHx_dy;
        }

        float e = eps[gidx];
        float s = sigma[gidx];
        float half_sdt_over_e = s * DTc / (2.0f * e);
        float Ap = 1.0f + half_sdt_over_e;
        float Am = 1.0f - half_sdt_over_e;
        float coefE = Am / Ap;
        float coefC = DTc / (e * Ap);

        Ex2[gidx] = coefE * Ex[gidx] + coefC * cx;
        Ey2[gidx] = coefE * Ey[gidx] + coefC * cy;
        Ez2[gidx] = coefE * Ez[gidx] + coefC * cz;
    }
}

extern "C" void kernel_launch(void* const* d_in, const int* in_sizes, int n_in,
                              void* d_out, int out_size, void* d_ws, size_t ws_size,
                              hipStream_t stream)
{
    // setup_inputs order: Ex, Ey, Ez, Hx, Hy, Hz, eps, mu, sigma
    const float* Ex    = (const float*)d_in[0];
    const float* Ey    = (const float*)d_in[1];
    const float* Ez    = (const float*)d_in[2];
    const float* Hx    = (const float*)d_in[3];
    const float* Hy    = (const float*)d_in[4];
    const float* Hz    = (const float*)d_in[5];
    const float* eps   = (const float*)d_in[6];
    const float* mu    = (const float*)d_in[7];
    const float* sigma = (const float*)d_in[8];

    // outputs concatenated flat in return order: ex2, ey2, ez2, hx2, hy2, hz2
    float* out = (float*)d_out;
    float* Ex2 = out + 0 * (size_t)N3;
    float* Ey2 = out + 1 * (size_t)N3;
    float* Ez2 = out + 2 * (size_t)N3;
    float* Hx2 = out + 3 * (size_t)N3;
    float* Hy2 = out + 4 * (size_t)N3;
    float* Hz2 = out + 5 * (size_t)N3;

    fdtd_fused<<<NBLK, 256, 0, stream>>>(Ex, Ey, Ez, Hx, Hy, Hz, eps, mu, sigma,
                                         Ex2, Ey2, Ez2, Hx2, Hy2, Hz2);
}

// Round 2
// 441.959 us; speedup vs baseline: 1.0446x; 1.0446x over previous
//
#include <hip/hip_runtime.h>

// 192^3 FDTD, FUSED + VECTORIZED: one kernel; step1 (E->H) computed on a
// tile+1-halo into LDS (z padded to float4-aligned chunks), step2 (H->E)
// from LDS. All global I/O is float4. Central differences only on the
// strict interior of all three dims; boundaries get zero curl contribution.
//
// Tile 8x8x32 interior (2048 pts), 256 threads, each thread owns 4-z chunks.
// Halo chunk grid 10x10x10 (z-extent 40, pads unused-but-computed).
// LDS: 3 fields x 10*10*40 floats = 48 KB -> 3 blocks/CU (12 waves).

#define NXD 192
#define NYD 192
#define NZD 192

static constexpr int   N3    = NXD * NYD * NZD;   // 7,077,888
static constexpr float DTc   = 1e-12f;
static constexpr float INV2D = 500.0f;            // 1/(2*1e-3)

// tile geometry
static constexpr int TX = 8, TY = 8, TZ = 32;
static constexpr int HXT = 10, HYT = 10;          // halo extents in x,y
static constexpr int ZCH = 10;                    // z chunks (40 floats, incl pads)
static constexpr int ZSTR = 40;                   // LDS z row stride (floats)
static constexpr int LVOL = HXT * HYT * ZSTR;     // 4000 floats per field
static constexpr int NCH  = HXT * HYT * ZCH;      // 1000 halo chunks
static constexpr int NBX = NXD / TX, NBY = NYD / TY, NBZ = NZD / TZ; // 24,24,6
static constexpr int NBLK = NBX * NBY * NBZ;      // 3456 (%8==0)

__device__ __forceinline__ int clampi(int v, int lo, int hi) {
    return v < lo ? lo : (v > hi ? hi : v);
}

__global__ __launch_bounds__(256, 3) void fdtd_fused(
    const float* __restrict__ Ex, const float* __restrict__ Ey, const float* __restrict__ Ez,
    const float* __restrict__ Hx, const float* __restrict__ Hy, const float* __restrict__ Hz,
    const float* __restrict__ eps, const float* __restrict__ mu, const float* __restrict__ sigma,
    float* __restrict__ Ex2, float* __restrict__ Ey2, float* __restrict__ Ez2,
    float* __restrict__ Hx2, float* __restrict__ Hy2, float* __restrict__ Hz2)
{
    __shared__ float sHx[LVOL];
    __shared__ float sHy[LVOL];
    __shared__ float sHz[LVOL];

    // XCD-bijective swizzle (3456 % 8 == 0): consecutive hw-dispatch bids on
    // one XCD get z-adjacent tiles -> halo overlap stays in that XCD's L2.
    int bid = blockIdx.x;
    int swz = (bid & 7) * (NBLK / 8) + (bid >> 3);
    int bz = swz % NBZ;
    int t0 = swz / NBZ;
    int by = t0 % NBY;
    int bx = t0 / NBY;
    int ox = bx * TX, oy = by * TY, oz = bz * TZ;

    int tid = threadIdx.x;

    // ---------------- phase 1: H2 on tile + halo -> LDS (float4 chunks) ----
    for (int it = 0; it < 4; ++it) {
        int h = tid + it * 256;
        if (h < NCH) {
            int cz = h % ZCH;
            int tt = h / ZCH;
            int hy = tt % HYT;
            int hx = tt / HYT;

            int gi = ox + hx - 1;
            int gj = oy + hy - 1;
            int kb = oz + cz * 4 - 4;              // true chunk base (may be OOB)

            int gic  = clampi(gi,     0, NXD - 1);
            int gjc  = clampi(gj,     0, NYD - 1);
            int gipc = clampi(gi + 1, 0, NXD - 1);
            int gimc = clampi(gi - 1, 0, NXD - 1);
            int gjpc = clampi(gj + 1, 0, NYD - 1);
            int gjmc = clampi(gj - 1, 0, NYD - 1);
            int kbc  = clampi(kb,     0, NZD - 4); // float4-aligned, in-bounds
            int km1  = clampi(kb - 1, 0, NZD - 1);
            int kp4  = clampi(kb + 4, 0, NZD - 1);

            int rowC  = (gic  * NYD + gjc ) * NZD;
            int rowXp = (gipc * NYD + gjc ) * NZD;
            int rowXm = (gimc * NYD + gjc ) * NZD;
            int rowYp = (gic  * NYD + gjpc) * NZD;
            int rowYm = (gic  * NYD + gjmc) * NZD;

            float4 ezYp = *(const float4*)(Ez + rowYp + kbc);
            float4 ezYm = *(const float4*)(Ez + rowYm + kbc);
            float4 exYp = *(const float4*)(Ex + rowYp + kbc);
            float4 exYm = *(const float4*)(Ex + rowYm + kbc);
            float4 eyXp = *(const float4*)(Ey + rowXp + kbc);
            float4 eyXm = *(const float4*)(Ey + rowXm + kbc);
            float4 ezXp = *(const float4*)(Ez + rowXp + kbc);
            float4 ezXm = *(const float4*)(Ez + rowXm + kbc);
            float4 eyC  = *(const float4*)(Ey + rowC + kbc);
            float4 exC  = *(const float4*)(Ex + rowC + kbc);
            float  ey_m1 = Ey[rowC + km1], ey_p4 = Ey[rowC + kp4];
            float  ex_m1 = Ex[rowC + km1], ex_p4 = Ex[rowC + kp4];
            float4 hxC = *(const float4*)(Hx + rowC + kbc);
            float4 hyC = *(const float4*)(Hy + rowC + kbc);
            float4 hzC = *(const float4*)(Hz + rowC + kbc);
            float4 muC = *(const float4*)(mu + rowC + kbc);

            const float* ezYpf = (const float*)&ezYp; const float* ezYmf = (const float*)&ezYm;
            const float* exYpf = (const float*)&exYp; const float* exYmf = (const float*)&exYm;
            const float* eyXpf = (const float*)&eyXp; const float* eyXmf = (const float*)&eyXm;
            const float* ezXpf = (const float*)&ezXp; const float* ezXmf = (const float*)&ezXm;
            const float* eyCf  = (const float*)&eyC;  const float* exCf  = (const float*)&exC;
            const float* hxCf  = (const float*)&hxC;  const float* hyCf  = (const float*)&hyC;
            const float* hzCf  = (const float*)&hzC;  const float* muCf  = (const float*)&muC;

            float4 vx, vy, vz;
            float* vxf = (float*)&vx; float* vyf = (float*)&vy; float* vzf = (float*)&vz;

            bool xyok = (gi >= 1) && (gi <= NXD - 2) && (gj >= 1) && (gj <= NYD - 2);
            #pragma unroll
            for (int e = 0; e < 4; ++e) {
                int ke = kb + e;
                bool valid = xyok && (ke >= 1) && (ke <= NZD - 2);
                float eyzm = (e == 0) ? ey_m1 : eyCf[e - 1];
                float eyzp = (e == 3) ? ey_p4 : eyCf[e + 1];
                float exzm = (e == 0) ? ex_m1 : exCf[e - 1];
                float exzp = (e == 3) ? ex_p4 : exCf[e + 1];
                float cx = valid ? ((ezYpf[e] - ezYmf[e]) - (eyzp - eyzm)) * INV2D : 0.0f;
                float cy = valid ? ((exzp - exzm) - (ezXpf[e] - ezXmf[e])) * INV2D : 0.0f;
                float cc = valid ? ((eyXpf[e] - eyXmf[e]) - (exYpf[e] - exYmf[e])) * INV2D : 0.0f;
                float f = DTc / muCf[e];
                vxf[e] = hxCf[e] - f * cx;
                vyf[e] = hyCf[e] - f * cy;
                vzf[e] = hzCf[e] - f * cc;
            }

            int l = (hx * HYT + hy) * ZSTR + cz * 4;
            *(float4*)(sHx + l) = vx;
            *(float4*)(sHy + l) = vy;
            *(float4*)(sHz + l) = vz;

            // tile chunks: store H2 outputs directly from registers
            if (hx >= 1 && hx <= TX && hy >= 1 && hy <= TY && cz >= 1 && cz <= 8) {
                int gidx = rowC + kb;  // coords are valid & unclamped here
                *(float4*)(Hx2 + gidx) = vx;
                *(float4*)(Hy2 + gidx) = vy;
                *(float4*)(Hz2 + gidx) = vz;
            }
        }
    }

    __syncthreads();

    // ---------------- phase 2: curl(H2) from LDS, E-update (float4) --------
    for (int it = 0; it < 2; ++it) {
        int c  = tid + it * 256;                  // 512 tile chunks
        int zc = c & 7;
        int tt = c >> 3;
        int iy = tt & 7;
        int ix = tt >> 3;
        int gi = ox + ix, gj = oy + iy;
        int k0 = oz + zc * 4;
        int gidx = (gi * NYD + gj) * NZD + k0;
        int l0 = ((ix + 1) * HYT + (iy + 1)) * ZSTR + zc * 4 + 4;

        float4 hzYp = *(const float4*)(sHz + l0 + ZSTR);
        float4 hzYm = *(const float4*)(sHz + l0 - ZSTR);
        float4 hxYp = *(const float4*)(sHx + l0 + ZSTR);
        float4 hxYm = *(const float4*)(sHx + l0 - ZSTR);
        float4 hzXp = *(const float4*)(sHz + l0 + HYT * ZSTR);
        float4 hzXm = *(const float4*)(sHz + l0 - HYT * ZSTR);
        float4 hyXp = *(const float4*)(sHy + l0 + HYT * ZSTR);
        float4 hyXm = *(const float4*)(sHy + l0 - HYT * ZSTR);
        float4 hyCv = *(const float4*)(sHy + l0);
        float4 hxCv = *(const float4*)(sHx + l0);
        float  hy_m1 = sHy[l0 - 1], hy_p4 = sHy[l0 + 4];
        float  hx_m1 = sHx[l0 - 1], hx_p4 = sHx[l0 + 4];

        float4 exC  = *(const float4*)(Ex + gidx);
        float4 eyC  = *(const float4*)(Ey + gidx);
        float4 ezC  = *(const float4*)(Ez + gidx);
        float4 epsC = *(const float4*)(eps + gidx);
        float4 sigC = *(const float4*)(sigma + gidx);

        const float* hzYpf = (const float*)&hzYp; const float* hzYmf = (const float*)&hzYm;
        const float* hxYpf = (const float*)&hxYp; const float* hxYmf = (const float*)&hxYm;
        const float* hzXpf = (const float*)&hzXp; const float* hzXmf = (const float*)&hzXm;
        const float* hyXpf = (const float*)&hyXp; const float* hyXmf = (const float*)&hyXm;
        const float* hyCf  = (const float*)&hyCv; const float* hxCf  = (const float*)&hxCv;
        const float* exCf  = (const float*)&exC;  const float* eyCf  = (const float*)&eyC;
        const float* ezCf  = (const float*)&ezC;
        const float* epsf  = (const float*)&epsC; const float* sigf  = (const float*)&sigC;

        float4 ex2, ey2, ez2;
        float* ex2f = (float*)&ex2; float* ey2f = (float*)&ey2; float* ez2f = (float*)&ez2;

        bool xyok = (gi >= 1) && (gi <= NXD - 2) && (gj >= 1) && (gj <= NYD - 2);
        #pragma unroll
        for (int e = 0; e < 4; ++e) {
            int ke = k0 + e;
            bool valid = xyok && (ke >= 1) && (ke <= NZD - 2);
            float hyzm = (e == 0) ? hy_m1 : hyCf[e - 1];
            float hyzp = (e == 3) ? hy_p4 : hyCf[e + 1];
            float hxzm = (e == 0) ? hx_m1 : hxCf[e - 1];
            float hxzp = (e == 3) ? hx_p4 : hxCf[e + 1];
            float cx = valid ? ((hzYpf[e] - hzYmf[e]) - (hyzp - hyzm)) * INV2D : 0.0f;
            float cy = valid ? ((hxzp - hxzm) - (hzXpf[e] - hzXmf[e])) * INV2D : 0.0f;
            float cc = valid ? ((hyXpf[e] - hyXmf[e]) - (hxYpf[e] - hxYmf[e])) * INV2D : 0.0f;

            float ee = epsf[e];
            float ss = sigf[e];
            float half_sdt_over_e = ss * DTc / (2.0f * ee);
            float Ap = 1.0f + half_sdt_over_e;
            float Am = 1.0f - half_sdt_over_e;
            float coefE = Am / Ap;
            float coefC = DTc / (ee * Ap);
            ex2f[e] = coefE * exCf[e] + coefC * cx;
            ey2f[e] = coefE * eyCf[e] + coefC * cy;
            ez2f[e] = coefE * ezCf[e] + coefC * cc;
        }

        *(float4*)(Ex2 + gidx) = ex2;
        *(float4*)(Ey2 + gidx) = ey2;
        *(float4*)(Ez2 + gidx) = ez2;
    }
}

extern "C" void kernel_launch(void* const* d_in, const int* in_sizes, int n_in,
                              void* d_out, int out_size, void* d_ws, size_t ws_size,
                              hipStream_t stream)
{
    // setup_inputs order: Ex, Ey, Ez, Hx, Hy, Hz, eps, mu, sigma
    const float* Ex    = (const float*)d_in[0];
    const float* Ey    = (const float*)d_in[1];
    const float* Ez    = (const float*)d_in[2];
    const float* Hx    = (const float*)d_in[3];
    const float* Hy    = (const float*)d_in[4];
    const float* Hz    = (const float*)d_in[5];
    const float* eps   = (const float*)d_in[6];
    const float* mu    = (const float*)d_in[7];
    const float* sigma = (const float*)d_in[8];

    // outputs concatenated flat in return order: ex2, ey2, ez2, hx2, hy2, hz2
    float* out = (float*)d_out;
    float* Ex2 = out + 0 * (size_t)N3;
    float* Ey2 = out + 1 * (size_t)N3;
    float* Ez2 = out + 2 * (size_t)N3;
    float* Hx2 = out + 3 * (size_t)N3;
    float* Hy2 = out + 4 * (size_t)N3;
    float* Hz2 = out + 5 * (size_t)N3;

    fdtd_fused<<<NBLK, 256, 0, stream>>>(Ex, Ey, Ez, Hx, Hy, Hz, eps, mu, sigma,
                                         Ex2, Ey2, Ez2, Hx2, Hy2, Hz2);
}